// Round 2
// baseline (614.865 us; speedup 1.0000x reference)
//
#include <hip/hip_runtime.h>

#define NTHREADS 256
#define SQRT2F 1.41421356237309504880f

// One block per environment. Work decomposition:
//   - 7 degrees l (K = 2l+1), Gram is 64x64, we need diag + upper triangle.
//   - 8x8 tiles over the 64x64 Gram -> 36 upper-tri tiles per l, 7*36 = 252
//     work items, one per thread (threads 252..255 idle in compute).
//   - Each thread holds its 8x8 accumulator in registers through the norm
//     reduction, so PS is computed exactly once (no recompute, no 58KB LDS).
// LDS: se rows padded to 16 floats (4 float4 chunks) with chunk-position XOR
// swizzle (c ^= (row>>3)&3) to break the power-of-2 row-stride bank conflict.
__global__ __launch_bounds__(NTHREADS, 2)
void ps_norm_kernel(const float* __restrict__ se0, const float* __restrict__ se1,
                    const float* __restrict__ se2, const float* __restrict__ se3,
                    const float* __restrict__ se4, const float* __restrict__ se5,
                    const float* __restrict__ se6, float* __restrict__ out)
{
    __shared__ __align__(16) float sse[7168];   // 7 * 64 rows * 16 floats
    __shared__ __align__(16) float stage[2080]; // per-l PS staging
    __shared__ float sred[8];

    const int tid = threadIdx.x;
    const int env = blockIdx.x;

    // ---- zero the se buffer (pad lanes must be 0.0 for the dot tails) ----
    {
        float4 z = make_float4(0.f, 0.f, 0.f, 0.f);
        float4* s4 = (float4*)sse;
        #pragma unroll
        for (int k = 0; k < 7; ++k) s4[tid + NTHREADS * k] = z;   // 1792 = 7*256
    }
    __syncthreads();

    // ---- stage se_l -> LDS, padded + swizzled; global reads are float4 ----
#define STAGE_SE(L, SRC) do {                                                   \
        constexpr int M  = 2*(L) + 1;                                           \
        constexpr int N4 = 16 * M;  /* 64*M floats / 4 */                       \
        const float4* __restrict__ p4 =                                         \
            (const float4*)((SRC) + (size_t)env * (64 * M));                    \
        for (int idx = tid; idx < N4; idx += NTHREADS) {                        \
            float4 v = p4[idx];                                                 \
            float vv[4] = {v.x, v.y, v.z, v.w};                                 \
            int e0 = idx * 4;                                                   \
            _Pragma("unroll")                                                   \
            for (int q = 0; q < 4; ++q) {                                       \
                int ee = e0 + q;                                                \
                int r  = ee / M;            /* row (a) */                       \
                int mm = ee - r * M;        /* position in row */               \
                int c  = mm >> 2;           /* logical float4 chunk */          \
                int f4i = (L)*256 + r*4 + (c ^ ((r >> 3) & 3));                 \
                sse[f4i*4 + (mm & 3)] = vv[q];                                  \
            }                                                                   \
        }                                                                       \
    } while (0)

    STAGE_SE(0, se0); STAGE_SE(1, se1); STAGE_SE(2, se2); STAGE_SE(3, se3);
    STAGE_SE(4, se4); STAGE_SE(5, se5); STAGE_SE(6, se6);
#undef STAGE_SE
    __syncthreads();

    // ---- map thread -> (tl, ta, tb): tile (ta,tb), ta<=tb, in 8x8 tile grid --
    int tl = 0, rem = tid;
    while (tl < 7 && rem >= 36) { rem -= 36; ++tl; }
    const bool active = (tl < 7);
    int ta = 0;
    while (rem >= 8 - ta) { rem -= 8 - ta; ++ta; }
    const int tb = ta + rem;

    float acc[8][8];
    #pragma unroll
    for (int i = 0; i < 8; ++i)
        #pragma unroll
        for (int j = 0; j < 8; ++j) acc[i][j] = 0.f;

    float rl = 0.f, s2rl = 0.f, sumsq = 0.f;

    if (active) {
        const int base4 = tl * 256;
        const int nch   = (tl >> 1) + 1;      // ceil((2l+1)/4)
        const int sa = ta & 3, sb = tb & 3;   // row-block swizzle keys
        const int arow0 = base4 + (8*ta) * 4;
        const int brow0 = base4 + (8*tb) * 4;
        for (int c = 0; c < nch; ++c) {
            float4 av[8], bv[8];
            #pragma unroll
            for (int i = 0; i < 8; ++i)
                av[i] = *(const float4*)&sse[4*(arow0 + i*4 + (c ^ sa))];
            #pragma unroll
            for (int j = 0; j < 8; ++j)
                bv[j] = *(const float4*)&sse[4*(brow0 + j*4 + (c ^ sb))];
            #pragma unroll
            for (int i = 0; i < 8; ++i) {
                #pragma unroll
                for (int j = 0; j < 8; ++j) {
                    acc[i][j] = fmaf(av[i].x, bv[j].x, acc[i][j]);
                    acc[i][j] = fmaf(av[i].y, bv[j].y, acc[i][j]);
                    acc[i][j] = fmaf(av[i].z, bv[j].z, acc[i][j]);
                    acc[i][j] = fmaf(av[i].w, bv[j].w, acc[i][j]);
                }
            }
        }
        rl   = 1.0f / sqrtf((float)(2*tl + 1));
        s2rl = SQRT2F * rl;
        #pragma unroll
        for (int i = 0; i < 8; ++i) {
            #pragma unroll
            for (int j = 0; j < 8; ++j) {
                const bool isdiag = (ta == tb) && (i == j);
                const bool valid  = (ta != tb) || (i <= j);
                const float sc = isdiag ? rl : s2rl;
                const float v  = sc * acc[i][j];
                if (valid) sumsq = fmaf(v, v, sumsq);
            }
        }
    }

    // ---- block-reduce sumsq -> inv norm (block-uniform) ----
    float s = sumsq;
    #pragma unroll
    for (int o = 32; o > 0; o >>= 1) s += __shfl_xor(s, o, 64);
    if ((tid & 63) == 0) sred[tid >> 6] = s;
    __syncthreads();
    if (tid == 0) {
        float tot = sred[0] + sred[1] + sred[2] + sred[3];
        sred[4] = 1.0f / fmaxf(sqrtf(tot), 1e-12f);
    }
    __syncthreads();
    const float inv = sred[4];

    // ---- emit: per l, scatter scaled values into LDS, coalesced store ----
    float4* __restrict__ dstbase = (float4*)(out + (size_t)env * 14560);
    #pragma unroll 1
    for (int l = 0; l < 7; ++l) {
        if (active && tl == l) {
            const float fo = s2rl * inv;   // off-diagonal scale
            const float fd = rl * inv;     // diagonal scale
            #pragma unroll
            for (int i = 0; i < 8; ++i) {
                const int a = 8*ta + i;
                // p(a,b) = 64 + a*(127-a)/2 + (b-a-1)
                const int pbase = 64 + ((a * (127 - a)) >> 1) - a - 1;
                #pragma unroll
                for (int j = 0; j < 8; ++j) {
                    const int b = 8*tb + j;
                    if (ta != tb || i < j)  stage[pbase + b] = fo * acc[i][j];
                    else if (i == j)        stage[a]         = fd * acc[i][i];
                }
            }
        }
        __syncthreads();
        const float4* st4 = (const float4*)stage;
        float4* dst4 = dstbase + l * 520;
        #pragma unroll
        for (int k2 = 0; k2 < 3; ++k2) {
            const int k = tid + NTHREADS * k2;
            if (k < 520) dst4[k] = st4[k];   // 520 = 2080/4
        }
        __syncthreads();
    }
}

extern "C" void kernel_launch(void* const* d_in, const int* in_sizes, int n_in,
                              void* d_out, int out_size, void* d_ws, size_t ws_size,
                              hipStream_t stream)
{
    const float* se0 = (const float*)d_in[0];
    const float* se1 = (const float*)d_in[1];
    const float* se2 = (const float*)d_in[2];
    const float* se3 = (const float*)d_in[3];
    const float* se4 = (const float*)d_in[4];
    const float* se5 = (const float*)d_in[5];
    const float* se6 = (const float*)d_in[6];
    float* out = (float*)d_out;

    const int J = in_sizes[0] / 64;   // se0 is [J, 64, 1]
    ps_norm_kernel<<<dim3(J), dim3(NTHREADS), 0, stream>>>(
        se0, se1, se2, se3, se4, se5, se6, out);
}